// Round 7
// baseline (62.738 us; speedup 1.0000x reference)
//
#include <hip/hip_runtime.h>
#include <utility>

#define BATCH 32768
#define NPHI 35

typedef float v2f __attribute__((ext_vector_type(2)));

// ---------- compile-time combinatorics ----------
constexpr int choose2(int n){ return (n*(n-1))/2; }

constexpr int tri_id_sorted(int a,int b,int c){
  int id=0;
  for(int x=0;x<a;++x) id += choose2(6-x);
  for(int y=a+1;y<b;++y) id += (6-y);
  id += (c-b-1);
  return id;
}

constexpr int tri_id3(int a,int b,int c){
  int x=a,y=b,z=c;
  if (x>y){int t=x;x=y;y=t;}
  if (y>z){int t=y;y=z;z=t;}
  if (x>y){int t=x;x=y;y=t;}
  return tri_id_sorted(x,y,z);
}

constexpr int sgn3(int a,int b,int c){
  int inv = (a>b)+(a>c)+(b>c);
  return (inv&1)? -1 : 1;
}

constexpr int UT(int i,int j){
  return i*7 - (i*(i-1))/2 + (j-i);
}

constexpr int PAIR(int k,int l){
  return k*7 - (k*(k+1))/2 + (l - k - 1);
}

// ---------- straight-line build program (1470 fma-like ops) ----------
struct Prog {
  int n;
  unsigned char kind[1472];
  unsigned char init[1472];   // kind0 only: first write to dst
  short         dst [1472];
  unsigned char a   [1472];
  short         b   [1472];
  signed char   s   [1472];
  unsigned char grp [1472];   // kl group 0..20 (each group is self-contained)
};

constexpr Prog build_prog(){
  Prog P{}; P.n=0;
  for(int k=0;k<7;++k) for(int l=k+1;l<7;++l){
    const int kl = PAIR(k,l);
    bool tinit[7]={};
    // ---- T phase for this (k,l)
    for(int m=0;m<7;++m) for(int n2=m+1;n2<7;++n2){
      if(m==k||m==l||n2==k||n2==l) continue;
      int comp[3]={0,0,0}; int cn=0;
      for(int x=0;x<7;++x) if(x!=k&&x!=l&&x!=m&&x!=n2){ comp[cn]=x; ++cn; }
      int perm[7]={k,l,m,n2,comp[0],comp[1],comp[2]};
      int invc=0;
      for(int i=0;i<7;++i) for(int j=i+1;j<7;++j) if(perm[i]>perm[j]) ++invc;
      const int es=(invc&1)? -1 : 1;
      const int tcomp=tri_id_sorted(comp[0],comp[1],comp[2]);
      for(int j=0;j<7;++j){
        if(j==m||j==n2) continue;
        P.kind[P.n]=0;
        P.init[P.n]=tinit[j]?0:1; tinit[j]=true;
        P.dst [P.n]=(short)(kl*7+j);
        P.a   [P.n]=(unsigned char)tcomp;
        P.b   [P.n]=(short)tri_id3(j,m,n2);
        P.s   [P.n]=(signed char)(es*sgn3(j,m,n2));
        P.grp [P.n]=(unsigned char)kl;
        ++P.n;
      }
    }
    // ---- B phase for this (k,l): U accumulated via fma (U pre-zeroed)
    for(int i=0;i<7;++i){
      if(i==k||i==l) continue;
      for(int j=i;j<7;++j){
        P.kind[P.n]=1;
        P.init[P.n]=0;
        P.dst [P.n]=(short)UT(i,j);
        P.a   [P.n]=(unsigned char)tri_id3(i,k,l);
        P.b   [P.n]=(short)(kl*7+j);
        P.s   [P.n]=(signed char)sgn3(i,k,l);
        P.grp [P.n]=(unsigned char)kl;
        ++P.n;
      }
    }
  }
  return P;
}

static constexpr Prog PROG = build_prog();
static_assert(PROG.n == 1470, "program size unexpected");

// 2-way partition of the 21 kl-groups (70 ops each).
// Main (phase 0) gets 11 groups (770 ops); helper (phase 1) gets 10 (700).
// Balanced so helper's 700 + ~35-instr LDS write ≈ main's 770 at the barrier.
constexpr int PHASE_OF[21] = {
  0,0,0,0,0,0,0,0,0,0,0,  // groups 0..10  -> main
  1,1,1,1,1,1,1,1,1,1     // groups 11..20 -> helper
};

// ---------- per-phase constant-index execution via fold expression ----------
template<int PH, int Q>
__device__ __forceinline__ void step_if(float (&T)[147], float (&U)[28],
                                        const float (&ph)[NPHI]){
  if constexpr (PHASE_OF[PROG.grp[Q]] == PH){
    if constexpr (Q > 0 && PROG.kind[Q] != PROG.kind[Q-1]) {
      __builtin_amdgcn_sched_barrier(0);
    }
    constexpr int  d = PROG.dst[Q];
    constexpr int  a = PROG.a[Q];
    constexpr int  b = PROG.b[Q];
    constexpr bool neg  = (PROG.s[Q] < 0);
    constexpr bool init = (PROG.init[Q] != 0);
    if constexpr (PROG.kind[Q] == 0){
      const float x = neg ? -ph[a] : ph[a];
      if constexpr (init) T[d] = x * ph[b];
      else                T[d] = fmaf(x, ph[b], T[d]);
    } else {
      const float x = neg ? -ph[a] : ph[a];
      U[d] = fmaf(x, T[b], U[d]);
    }
  }
}

template<int PH, int... Q>
__device__ __forceinline__ void run_phase(float (&T)[147], float (&U)[28],
                                          const float (&ph)[NPHI],
                                          std::integer_sequence<int, Q...>){
  (step_if<PH, Q>(T, U, ph), ...);
}

// one Jacobi rotation — half-angle c,s + baseline-exact diagonal update
// (R6 form verbatim: passed at absmax 2.0).
#define ROT_BODY(p1, q1, GUARD)                                               \
  {                                                                           \
    const float apq = A[UT(p1,q1)];                                           \
    const float app = A[UT(p1,p1)];                                           \
    const float aqq = A[UT(q1,q1)];                                           \
    bool doit = true;                                                         \
    if (GUARD) doit = __any(fabsf(apq) > 1e-6f*(fabsf(app)+fabsf(aqq)));      \
    if (doit) {                                                               \
      const float x   = aqq - app;                                            \
      const float y   = apq + apq;                                            \
      const float ax  = fabsf(x) + 1e-18f;                                    \
      const float ss  = fmaf(ax, ax, y*y);         /* r^2, normal */          \
      const float w   = __builtin_amdgcn_rsqf(ss); /* 1/r */                  \
      const float u   = ax * w;                    /* cos2t in (0,1] */       \
      const float r1  = ss * w;                    /* r = sqrt(ss) */         \
      const float c   = __builtin_amdgcn_sqrtf(fmaf(0.5f, u, 0.5f));          \
      const float tm  = fabsf(y) * __builtin_amdgcn_rcpf(ax + r1); /* |t| */  \
      const unsigned sb = (__float_as_uint(x) ^ __float_as_uint(y))           \
                          & 0x80000000u;                                      \
      const float t   = __uint_as_float(__float_as_uint(tm) ^ sb);            \
      const float s1  = t * c;                                                \
      A[UT(p1,p1)] = fmaf(-t, apq, app);                                      \
      A[UT(q1,q1)] = fmaf( t, apq, aqq);                                      \
      A[UT(p1,q1)] = 0.0f;                                                    \
      const v2f cs2 = {  c, s1 };                                             \
      const v2f msc = { -s1, c };                                             \
      _Pragma("unroll")                                                       \
      for (int r=0;r<7;++r){                                                  \
        if (r==p1 || r==q1) continue;                                         \
        const int irp = (r<p1)? UT(r,p1) : UT(p1,r);                          \
        const int irq = (r<q1)? UT(r,q1) : UT(q1,r);                          \
        const v2f arp2 = { A[irp], A[irp] };                                  \
        const v2f arq2 = { A[irq], A[irq] };                                  \
        const v2f res = __builtin_elementwise_fma(cs2, arp2, msc*arq2);       \
        A[irp] = res.x;                                                       \
        A[irq] = res.y;                                                       \
      }                                                                       \
    }                                                                         \
  }

// ---------- kernel: 2 waves per 64 samples; 512 blocks × 2 = 1024 waves
// = exactly 1 wave/SIMD. Helper does 10/21 of the build and exits; main
// keeps its SIMD private for the serial Jacobi. ----------
__global__ __launch_bounds__(128,1)
void PositivityConstraint_89086211654295_kernel(const float* __restrict__ phi,
                                                float* __restrict__ out){
  const int wv  = threadIdx.x >> 6;        // 0 = main, 1 = helper
  const int ln  = threadIdx.x & 63;
  const int gid = blockIdx.x*64 + ln;      // BATCH == 512*64 exactly

  // [64][30]: rows 120 B (8B-aligned for v2f), dword-stride 30 vs 32 banks
  // -> worst 2-way aliasing (free per m136). 7680 B total.
  __shared__ float Upart[64][30];

  const float* __restrict__ p = phi + (size_t)gid * NPHI;
  float ph[NPHI];
  {
    const float4* __restrict__ p4 = reinterpret_cast<const float4*>(p);
    #pragma unroll
    for (int k=0;k<8;++k){
      const float4 v = p4[k];
      ph[4*k+0]=v.x; ph[4*k+1]=v.y; ph[4*k+2]=v.z; ph[4*k+3]=v.w;
    }
    ph[32]=p[32]; ph[33]=p[33]; ph[34]=p[34];
  }

  float T[147];
  float U[28];
  #pragma unroll
  for (int i=0;i<28;++i) U[i] = 0.0f;

  if (wv == 0){
    run_phase<0>(T,U,ph, std::make_integer_sequence<int,PROG.n>{});
  } else {
    run_phase<1>(T,U,ph, std::make_integer_sequence<int,PROG.n>{});
    v2f* __restrict__ row = reinterpret_cast<v2f*>(&Upart[ln][0]);
    #pragma unroll
    for (int k=0;k<14;++k){ v2f t = { U[2*k], U[2*k+1] }; row[k] = t; }
  }
  __syncthreads();
  if (wv) return;

  // main: accumulate helper partial
  {
    const v2f* __restrict__ row = reinterpret_cast<const v2f*>(&Upart[ln][0]);
    #pragma unroll
    for (int k=0;k<14;++k){
      const v2f t = row[k];
      U[2*k]   += t.x;
      U[2*k+1] += t.y;
    }
  }

  float A[28];
  #pragma unroll
  for (int i=0;i<28;++i) A[i] = U[i]*(1.0f/6.0f);

  // Cyclic Jacobi: 4 full sweeps + 1 skip-guarded polish pass (R6 verbatim).
  #pragma unroll 1
  for (int sweep=0; sweep<4; ++sweep){
    #pragma unroll
    for (int p1=0;p1<7;++p1){
      #pragma unroll
      for (int q1=p1+1;q1<7;++q1){
        ROT_BODY(p1, q1, false)
      }
    }
  }
  { // polish pass
    #pragma unroll
    for (int p1=0;p1<7;++p1){
      #pragma unroll
      for (int q1=p1+1;q1<7;++q1){
        ROT_BODY(p1, q1, true)
      }
    }
  }

  // det(B) = product of eigenvalues; eig(g) = eig(B) / (|det|+1e-12)^(1/9)
  float det = 1.0f;
  #pragma unroll
  for (int i=0;i<7;++i) det *= A[UT(i,i)];
  const float ad = fabsf(det) + 1e-12f;
  const float scale = __builtin_amdgcn_exp2f(__builtin_amdgcn_logf(ad) * (1.0f/9.0f));
  const float inv = __builtin_amdgcn_rcpf(scale);

  float sum = 0.0f;
  #pragma unroll
  for (int i=0;i<7;++i){
    const float ev = A[UT(i,i)]*inv;
    const float r = 1e-6f - ev;
    sum += fmaxf(r, 0.0f);
  }
  out[gid] = sum;
}

// ---------- launch ----------
extern "C" void kernel_launch(void* const* d_in, const int* in_sizes, int n_in,
                              void* d_out, int out_size, void* d_ws, size_t ws_size,
                              hipStream_t stream) {
  const float* phi = (const float*)d_in[0];
  float* out = (float*)d_out;
  (void)in_sizes; (void)n_in; (void)out_size; (void)d_ws; (void)ws_size;
  hipLaunchKernelGGL(PositivityConstraint_89086211654295_kernel,
                     dim3(BATCH/64), dim3(128), 0, stream, phi, out);
}